// Round 6
// baseline (185.602 us; speedup 1.0000x reference)
//
#include <hip/hip_runtime.h>
#include <hip/hip_bf16.h>

// GCK 3x3 conv == plain 3x3 conv with W_eff = basis · linCombs.
// Streaming fused implicit GEMM: M=O=64, N=512*512, K=C*9=576, bf16 MFMA.
// 256 blocks = 64 row-tiles x 4 col-tiles(128px). Each block streams 8 output
// rows through a 4-slot LDS ring of bf16 channels-last input rows (130x64ch).
// Pipeline per step: issue loads row i+3 -> compute row i -> barrier ->
// convert+ds_write row i+3 -> barrier. Weights persistent in VGPRs
// (36 x short8 per wave = its 32-o slice of all 18 K-slices).

constexpr int kC = 64, kO = 64;
constexpr int kH = 514, kW = 514;
constexpr int kHO = 512, kWO = 512;
constexpr int kNPIX = kH * kW;          // 264196

constexpr int TPX   = 128;   // pixels (cols) per block
constexpr int TROWS = 8;     // output rows per block
constexpr int LCOLS = 130;   // staged cols (128 + 2 halo)
constexpr int SLOT  = LCOLS * 64;   // shorts per ring slot (8320)

typedef __attribute__((ext_vector_type(8))) short short8;    // 8 bf16
typedef __attribute__((ext_vector_type(4))) float floatx4;   // 4 fp32 acc

__device__ inline unsigned short f2bf(float f) {
    unsigned int u = __float_as_uint(f);
    unsigned int r = (u + 0x7fffu + ((u >> 16) & 1u)) >> 16;  // RN-even
    return (unsigned short)r;
}

// ---------------------------------------------------------------- weight prep
// W_eff[o,c,3r+s] = sum_{i,j} lin[o, c*9+3i+j] * V[i,r]*V[j,s]
// stored pre-swizzled into MFMA A-fragment order:
//   kglob = tap*64 + c ; ks = kglob>>5 ; kg = (kglob>>3)&3 ; e = kglob&7
//   w2[ ((ks*4+kg)*64 + o)*8 + e ] = bf16(W_eff)
__global__ void gck_wprep(const float* __restrict__ lin, unsigned short* __restrict__ w2) {
    int t = blockIdx.x * 256 + threadIdx.x;
    if (t >= kO * kC * 9) return;
    int tap = t % 9;
    int c   = (t / 9) % kC;
    int o   = t / (9 * kC);
    int r = tap / 3, s = tap % 3;
    const float Vm[3][3] = {{1.f, 1.f, 1.f}, {1.f, -1.f, 1.f}, {1.f, 1.f, -1.f}};
    float acc = 0.f;
#pragma unroll
    for (int i = 0; i < 3; i++)
#pragma unroll
        for (int j = 0; j < 3; j++)
            acc += lin[o * (kC * 9) + c * 9 + 3 * i + j] * Vm[i][r] * Vm[j][s];
    int kglob = tap * 64 + c;
    int ks = kglob >> 5, kg = (kglob >> 3) & 3, e = kglob & 7;
    w2[((ks * 4 + kg) * 64 + o) * 8 + e] = f2bf(acc);
}

// ---- staging helpers: one input row (130 cols x 64 ch) per block-step.
// thread t: col quad q=t&31 (cols 4q..4q+3), channel octet cg=t>>5 (ch 8cg..+7).
// LDS slot layout: xs[(slot_row*130 + col)*64 + swz(unit,col)*8 + (ch&7)]
//   swz = unit ^ (col&7) ^ ((col>>3)&7)  -> 8 distinct 16B slots per 16 lanes
//   on BOTH ds_write_b128 (store) and ds_read_b128 (B-fragment) sides.
__device__ inline void stage_load(const float* __restrict__ x, int grow, int wbase,
                                  int q, int cg, int t, float (&v)[8][4], float& ev) {
    const float* gp = x + (size_t)grow * kW + wbase + q * 4;
    const int ch0 = cg * 8;
    if ((grow & 1) == 0) {                    // even input row: 16B aligned
#pragma unroll
        for (int c = 0; c < 8; ++c) {
            float4 f = *reinterpret_cast<const float4*>(gp + (size_t)(ch0 + c) * kNPIX);
            v[c][0] = f.x; v[c][1] = f.y; v[c][2] = f.z; v[c][3] = f.w;
        }
    } else {                                  // odd row: 8B aligned (kW=514)
#pragma unroll
        for (int c = 0; c < 8; ++c) {
            const float* p = gp + (size_t)(ch0 + c) * kNPIX;
            float2 f0 = *reinterpret_cast<const float2*>(p);
            float2 f1 = *reinterpret_cast<const float2*>(p + 2);
            v[c][0] = f0.x; v[c][1] = f0.y; v[c][2] = f1.x; v[c][3] = f1.y;
        }
    }
    if (t < 128) {                            // halo cols 128,129
        int ch = t & 63, col = 128 + (t >> 6);
        ev = x[(size_t)ch * kNPIX + (size_t)grow * kW + wbase + col];
    }
}

__device__ inline void stage_write(unsigned short* xs, int slot_row, int q, int cg, int t,
                                   const float (&v)[8][4], float ev) {
#pragma unroll
    for (int j = 0; j < 4; ++j) {
        int col = q * 4 + j;
        short8 u8;
#pragma unroll
        for (int c = 0; c < 8; ++c) u8[c] = (short)f2bf(v[c][j]);
        int swz = (cg ^ (col & 7) ^ ((col >> 3) & 7)) & 7;
        *reinterpret_cast<short8*>(&xs[(slot_row * LCOLS + col) * 64 + swz * 8]) = u8;
    }
    if (t < 128) {
        int ch = t & 63, col = 128 + (t >> 6);
        int swz = ((ch >> 3) ^ (col & 7) ^ ((col >> 3) & 7)) & 7;
        xs[(slot_row * LCOLS + col) * 64 + swz * 8 + (ch & 7)] = f2bf(ev);
    }
}

// ------------------------------------------------------------- streaming conv
__global__ __launch_bounds__(256, 2) void gck_stream(const float* __restrict__ x,
                                                     const unsigned short* __restrict__ w2,
                                                     float* __restrict__ out) {
    __shared__ unsigned short xs[4 * SLOT];   // 66.6 KiB ring

    const int bid = blockIdx.x;
    // XCD-chunked: XCD k gets one ct-column, contiguous rt band -> halo in-XCD L2
    const int xcd = bid & 7, jj = bid >> 3;
    const int ct = xcd & 3;
    const int rt = (xcd >> 2) * 32 + jj;
    const int wbase = ct * TPX;
    const int hbase = rt * TROWS;

    const int t    = threadIdx.x;
    const int wave = t >> 6;
    const int lane = t & 63;
    const int l16  = lane & 15;
    const int kg   = lane >> 4;
    const int o0   = (wave & 1) * 32;         // wave's 32-o slice
    const int px0  = (wave >> 1) * 64;        // wave's 64-px slice

    const int q  = t & 31;                    // staging col quad
    const int cg = t >> 5;                    // staging channel octet

    // ---- A persistent in registers: 18 ks x 2 m fragments
    const short8* w2v = reinterpret_cast<const short8*>(w2);
    short8 a[18][2];
#pragma unroll
    for (int ks = 0; ks < 18; ++ks)
#pragma unroll
        for (int m = 0; m < 2; ++m)
            a[ks][m] = w2v[(ks * 4 + kg) * 64 + o0 + m * 16 + l16];

    // ---- prologue: stage input rows 0..2 into slots 0..2
    float v[8][4]; float ev = 0.f;
#pragma unroll
    for (int r = 0; r < 3; ++r) {
        stage_load(x, hbase + r, wbase, q, cg, t, v, ev);
        stage_write(xs, r, q, cg, t, v, ev);
    }
    __syncthreads();

    floatx4 acc[2][4];
#pragma unroll
    for (int m = 0; m < 2; m++)
#pragma unroll
        for (int n = 0; n < 4; n++) acc[m][n] = (floatx4){0.f, 0.f, 0.f, 0.f};

    for (int i = 0; i < TROWS; ++i) {
        const bool pf = (i + 3 < 10);         // rows 3..9 prefetched at i=0..6
        if (pf) stage_load(x, hbase + i + 3, wbase, q, cg, t, v, ev);

        // ---- compute output row i from ring slots i..i+2
#pragma unroll
        for (int ks = 0; ks < 18; ++ks) {
            const int tap = ks >> 1;
            const int tr  = tap / 3;
            const int s   = tap - tr * 3;
            const int u   = (ks & 1) * 4 + kg;
            const int srow = (i + tr) & 3;
            short8 b[4];
#pragma unroll
            for (int n = 0; n < 4; ++n) {
                int col = px0 + n * 16 + l16 + s;          // 0..129
                int swz = (u ^ (col & 7) ^ ((col >> 3) & 7)) & 7;
                b[n] = *reinterpret_cast<const short8*>(&xs[(srow * LCOLS + col) * 64 + swz * 8]);
            }
#pragma unroll
            for (int m = 0; m < 2; ++m)
#pragma unroll
                for (int n = 0; n < 4; ++n)
                    acc[m][n] = __builtin_amdgcn_mfma_f32_16x16x32_bf16(a[ks][m], b[n], acc[m][n], 0, 0, 0);
        }

        // ---- store output row i; D: row(o)=kg*4+j, col(px)=l16
        const int h = hbase + i;
#pragma unroll
        for (int m = 0; m < 2; ++m)
#pragma unroll
            for (int n = 0; n < 4; ++n) {
                int col = wbase + px0 + n * 16 + l16;
#pragma unroll
                for (int j = 0; j < 4; ++j) {
                    int o = o0 + m * 16 + kg * 4 + j;
                    out[((size_t)o * kHO + h) * kWO + col] = acc[m][n][j];
                }
                acc[m][n] = (floatx4){0.f, 0.f, 0.f, 0.f};
            }

        __syncthreads();                       // all waves done reading old slot
        if (pf) stage_write(xs, (i + 3) & 3, q, cg, t, v, ev);
        __syncthreads();                       // row i+3 visible for step i+1
    }
}

extern "C" void kernel_launch(void* const* d_in, const int* in_sizes, int n_in,
                              void* d_out, int out_size, void* d_ws, size_t ws_size,
                              hipStream_t stream) {
    const float* x   = (const float*)d_in[0];   // (1,64,514,514) fp32
    const float* lin = (const float*)d_in[1];   // (64,576) fp32
    float* out = (float*)d_out;                 // (1,64,512,512) fp32

    unsigned short* w2 = (unsigned short*)d_ws; // 72 KiB

    gck_wprep<<<(kO * kC * 9 + 255) / 256, 256, 0, stream>>>(lin, w2);
    gck_stream<<<256, 256, 0, stream>>>(x, w2, out);
}

// Round 8
// 142.227 us; speedup vs baseline: 1.3050x; 1.3050x over previous
//
#include <hip/hip_runtime.h>
#include <hip/hip_bf16.h>

// GCK 3x3 conv == plain 3x3 conv with W_eff = basis · linCombs.
// FUSED implicit GEMM: M=O=64, N=512*512, K=C*9=576, bf16 MFMA 16x16x32.
// R7: high-TLP variant. 2048 blocks = 256 row-tiles(2 out rows) x 8 col-tiles
// (64 px, ct = bid&7 -> one column stripe per XCD; rt+-1 halo hits same-XCD L2).
// LDS = 4 rows x 66 cols x 64 ch bf16 (33 KB) -> 4 blocks/CU, 16 waves/CU.
// Staging: thread owns 8ch x 2col, 8x float2 loads (8B-aligned always),
// writes full short8 granules; 3-term XOR swizzle -> b128 write AND read
// spread 64 lanes over 8 slots (LDS floor, <=2-way residual).

constexpr int kC = 64, kO = 64;
constexpr int kH = 514, kW = 514;
constexpr int kHO = 512, kWO = 512;
constexpr int kNPIX = kH * kW;          // 264196
constexpr int LCOLS = 66;

typedef __attribute__((ext_vector_type(8))) short short8;    // 8 bf16
typedef __attribute__((ext_vector_type(4))) float floatx4;   // 4 fp32 acc

__device__ inline unsigned short f2bf(float f) {
    unsigned int u = __float_as_uint(f);
    unsigned int r = (u + 0x7fffu + ((u >> 16) & 1u)) >> 16;  // RN-even
    return (unsigned short)r;
}

// ---------------------------------------------------------------- weight prep
// W_eff[o,c,3r+s] = sum_{i,j} lin[o, c*9+3i+j] * V[i,r]*V[j,s]
// stored pre-swizzled into MFMA A-fragment order:
//   kglob = tap*64 + c ; ks = kglob>>5 ; kg = (kglob>>3)&3 ; e = kglob&7
//   w2[ ((ks*4+kg)*64 + o)*8 + e ] = bf16(W_eff)
__global__ void gck_wprep(const float* __restrict__ lin, unsigned short* __restrict__ w2) {
    int t = blockIdx.x * 256 + threadIdx.x;
    if (t >= kO * kC * 9) return;
    int tap = t % 9;
    int c   = (t / 9) % kC;
    int o   = t / (9 * kC);
    int r = tap / 3, s = tap % 3;
    const float Vm[3][3] = {{1.f, 1.f, 1.f}, {1.f, -1.f, 1.f}, {1.f, 1.f, -1.f}};
    float acc = 0.f;
#pragma unroll
    for (int i = 0; i < 3; i++)
#pragma unroll
        for (int j = 0; j < 3; j++)
            acc += lin[o * (kC * 9) + c * 9 + 3 * i + j] * Vm[i][r] * Vm[j][s];
    int kglob = tap * 64 + c;
    int ks = kglob >> 5, kg = (kglob >> 3) & 3, e = kglob & 7;
    w2[((ks * 4 + kg) * 64 + o) * 8 + e] = f2bf(acc);
}

// ------------------------------------------------------------- fused conv
__global__ __launch_bounds__(256, 4) void gck_conv(const float* __restrict__ x,
                                                   const unsigned short* __restrict__ w2,
                                                   float* __restrict__ out) {
    __shared__ unsigned short xs[4 * LCOLS * 64];   // 33 KiB -> 4 blocks/CU

    const int bid = blockIdx.x;
    const int ct = bid & 7;          // XCD-aligned column stripe
    const int rt = bid >> 3;
    const int hbase = rt * 2;
    const int wbase = ct * 64;
    const int t    = threadIdx.x;
    const int wave = t >> 6;
    const int lane = t & 63;
    const int l16  = lane & 15;
    const int kg   = lane >> 4;
    const int hw   = wave >> 1;      // local output row 0..1
    const int o0   = (wave & 1) * 32;

    // ---- stage 4 input rows: thread owns ch-octet cg (8 ch) x col-pair cp
    {
        const int cp  = t & 31;
        const int cg  = t >> 5;
        const int ch0 = cg * 8;
        const int colb = cp * 2;
#pragma unroll
        for (int r = 0; r < 4; ++r) {
            const float* gp = x + (size_t)(hbase + r) * kW + wbase + colb;
            float2 f[8];
#pragma unroll
            for (int c = 0; c < 8; ++c)
                f[c] = *reinterpret_cast<const float2*>(gp + (size_t)(ch0 + c) * kNPIX);
#pragma unroll
            for (int j = 0; j < 2; ++j) {
                int col = colb + j;
                short8 u8;
#pragma unroll
                for (int c = 0; c < 8; ++c) u8[c] = (short)f2bf(j ? f[c].y : f[c].x);
                int swz = (cg ^ (col & 7) ^ ((col >> 3) & 7)) & 7;
                *reinterpret_cast<short8*>(&xs[(r * LCOLS + col) * 64 + swz * 8]) = u8;
            }
        }
        // halo cols 64,65 : 4 rows x 64 ch x 2 cols = 512 elements
#pragma unroll
        for (int j = 0; j < 2; ++j) {
            int idx = j * 256 + t;               // 0..511
            int col = 64 + (idx & 1);
            int ch  = (idx >> 1) & 63;
            int r   = idx >> 7;
            float f = x[(size_t)ch * kNPIX + (size_t)(hbase + r) * kW + wbase + col];
            int swz = ((ch >> 3) ^ (col & 7) ^ ((col >> 3) & 7)) & 7;
            xs[(r * LCOLS + col) * 64 + swz * 8 + (ch & 7)] = f2bf(f);
        }
    }
    __syncthreads();

    floatx4 acc[2][4];
#pragma unroll
    for (int m = 0; m < 2; m++)
#pragma unroll
        for (int n = 0; n < 4; n++) acc[m][n] = (floatx4){0.f, 0.f, 0.f, 0.f};

    const short8* w2v = reinterpret_cast<const short8*>(w2);

    // A prefetch (global, L2-resident 72 KiB)
    short8 a_cur[2];
#pragma unroll
    for (int m = 0; m < 2; m++) a_cur[m] = w2v[(0 * 4 + kg) * 64 + o0 + m * 16 + l16];

#pragma unroll 2
    for (int ks = 0; ks < 18; ++ks) {
        int tap = ks >> 1;
        int r0  = tap / 3;
        int s   = tap - r0 * 3;

        short8 a_nxt[2];
        int ksn = (ks < 17) ? ks + 1 : ks;
#pragma unroll
        for (int m = 0; m < 2; m++) a_nxt[m] = w2v[(ksn * 4 + kg) * 64 + o0 + m * 16 + l16];

        int rr = hw + r0;                      // staged row 0..3
        int u  = (ks & 1) * 4 + kg;            // 16B ch-octet 0..7
        short8 b[4];
#pragma unroll
        for (int n = 0; n < 4; ++n) {
            int col  = n * 16 + l16 + s;       // 0..65
            int swz  = (u ^ (col & 7) ^ ((col >> 3) & 7)) & 7;
            b[n] = *reinterpret_cast<const short8*>(&xs[(rr * LCOLS + col) * 64 + swz * 8]);
        }

#pragma unroll
        for (int m = 0; m < 2; m++)
#pragma unroll
            for (int n = 0; n < 4; n++)
                acc[m][n] = __builtin_amdgcn_mfma_f32_16x16x32_bf16(a_cur[m], b[n], acc[m][n], 0, 0, 0);

#pragma unroll
        for (int m = 0; m < 2; m++) a_cur[m] = a_nxt[m];
    }

    // epilogue: D row(o) = o0 + m*16 + kg*4 + j, col(px) = wbase + n*16 + l16
    const int h = hbase + hw;
#pragma unroll
    for (int m = 0; m < 2; m++) {
#pragma unroll
        for (int n = 0; n < 4; n++) {
            int wcol = wbase + n * 16 + l16;
#pragma unroll
            for (int j = 0; j < 4; j++) {
                int o = o0 + m * 16 + kg * 4 + j;
                out[((size_t)o * kHO + h) * kWO + wcol] = acc[m][n][j];
            }
        }
    }
}

extern "C" void kernel_launch(void* const* d_in, const int* in_sizes, int n_in,
                              void* d_out, int out_size, void* d_ws, size_t ws_size,
                              hipStream_t stream) {
    const float* x   = (const float*)d_in[0];   // (1,64,514,514) fp32
    const float* lin = (const float*)d_in[1];   // (64,576) fp32
    float* out = (float*)d_out;                 // (1,64,512,512) fp32

    unsigned short* w2 = (unsigned short*)d_ws; // 72 KiB

    gck_wprep<<<(kO * kC * 9 + 255) / 256, 256, 0, stream>>>(lin, w2);
    gck_conv<<<(kHO / 2) * 8, 256, 0, stream>>>(x, w2, out);
}